// Round 2
// baseline (550.149 us; speedup 1.0000x reference)
//
#include <hip/hip_runtime.h>
#include <hip/hip_cooperative_groups.h>

namespace cg = cooperative_groups;

#define EPS 1e-4f
#define ITERS 6
#define INVN (1.0f/512.0f)

// ws layout (bytes):
// det:0  invES:256  u:4096(16KB)  v:20480(16KB)  bsum:36864  a:69632(512KB)  bv:593920(512KB)

__global__ void __launch_bounds__(256)
sinkhorn_fused(const float* __restrict__ emb_in, const void* __restrict__ maskp,
               const float* __restrict__ emb_out, const float* __restrict__ pad,
               const float* __restrict__ pos, const float* __restrict__ Win,
               const float* __restrict__ bin, const float* __restrict__ Wout,
               const float* __restrict__ bout, float* __restrict__ C,
               char* __restrict__ ws) {
  cg::grid_group grid = cg::this_grid();
  int t = threadIdx.x;
  int blk = blockIdx.x;
  int* det   = (int*)ws;
  float* invES = (float*)(ws + 256);
  float* u     = (float*)(ws + 4096);
  float* v     = (float*)(ws + 20480);
  float* bsum  = (float*)(ws + 36864);
  float* a     = (float*)(ws + 69632);
  float* bv    = (float*)(ws + 593920);

  __shared__ unsigned dsh[2];
  __shared__ float as_[16][33], bs_[16][33];
  __shared__ float rs[256];
  __shared__ float red[16][17];

  // ---- Phase 0: mask element-size detection (block 0 inspects first 4KB) ----
  if (blk == 0) {
    if (t == 0) { dsh[0] = 0u; dsh[1] = 0u; }
    __syncthreads();
    const unsigned char* m = (const unsigned char*)maskp;
    unsigned orb = 0, orc = 0;
    for (int i = t * 16; i < t * 16 + 16; ++i) {
      unsigned val = m[i];
      if (i & 3) orb |= val;            // nonzero only if 1-byte elements
      if ((i & 7) == 4) orc |= val;     // nonzero only if 4-byte elements
    }
    atomicOr(&dsh[0], orb);
    atomicOr(&dsh[1], orc);
    __syncthreads();
    if (t == 0) det[0] = dsh[0] ? 0 : (dsh[1] ? 1 : 2);  // 0=bool,1=i32,2=i64
  }
  grid.sync();

  // ---- Phase 1: a = (emb_out+pos)@Wout+bout ; b = where(mask,pad,emb_in)@Win+bin
  {
    int dv = det[0];
    for (int rep = 0; rep < 2; ++rep) {
      int w = blk * 512 + rep * 256 + t;   // 0..131071 (node,m) units
      int g = w >> 5, m = w & 31, n = g & 511;
      int mv;
      if (dv == 0)      mv = ((const unsigned char*)maskp)[g];
      else if (dv == 1) mv = ((const int*)maskp)[g];
      else              mv = (int)((const long long*)maskp)[g];
      float aa = bout[m], bb = bin[m];
      const float* eo = emb_out + (size_t)g * 256;
      const float* ei = emb_in  + (size_t)g * 256;
      const float* pp = pos     + (size_t)n * 256;
      for (int d = 0; d < 256; ++d) {
        aa = fmaf(eo[d] + pp[d], Wout[d * 32 + m], aa);
        bb = fmaf(mv ? pad[d] : ei[d], Win[d * 32 + m], bb);
      }
      a[g * 32 + m]  = aa;
      bv[g * 32 + m] = bb;
    }
  }
  grid.sync();

  // ---- Phase 2: C[b,i,j] = sum_m |a-bv| ; per-block partial sums (32 tiles each)
  {
    float myacc = 0.f;
    int ty = t >> 4, tx = t & 15;
    for (int tl = 0; tl < 32; ++tl) {
      int bt = blk * 32 + tl;
      int batch = bt >> 10, ti = bt & 1023;
      int it = ti >> 5, jt = ti & 31;
      for (int k = t; k < 512; k += 256) {
        int r = k >> 5, m = k & 31;
        as_[r][m] = a [(batch * 512 + it * 16 + r) * 32 + m];
        bs_[r][m] = bv[(batch * 512 + jt * 16 + r) * 32 + m];
      }
      __syncthreads();
      float s = 0.f;
#pragma unroll
      for (int m = 0; m < 32; ++m) s += fabsf(as_[ty][m] - bs_[tx][m]);
      C[(size_t)(batch * 512 + it * 16 + ty) * 512 + jt * 16 + tx] = s;
      myacc += s;
      __syncthreads();
    }
    rs[t] = myacc;
    __syncthreads();
    for (int off = 128; off; off >>= 1) {
      if (t < off) rs[t] += rs[t + off];
      __syncthreads();
    }
    if (t == 0) bsum[blk] = rs[0];
  }
  grid.sync();

  // ---- Phase 3: invES[b] = -1/(EPS * S_b)  (blocks 0..7 reduce 32 partials)
  if (blk < 8) {
    rs[t] = (t < 32) ? bsum[blk * 32 + t] : 0.f;
    __syncthreads();
    for (int off = 128; off; off >>= 1) {
      if (t < off) rs[t] += rs[t + off];
      __syncthreads();
    }
    if (t == 0) invES[blk] = -1.0f / (EPS * rs[0]);
  }
  grid.sync();

  int wv = t >> 6, lane = t & 63;

  // ---- Phase 4: row pass 1 fused with K=exp(C*invES) (v implicit = 1)
  for (int rr = 0; rr < 4; ++rr) {
    int row = blk * 16 + wv * 4 + rr;       // global row 0..4095
    float s = invES[row >> 9];
    float4* Kr = (float4*)(C + (size_t)row * 512);
    float4 x0 = Kr[lane], x1 = Kr[lane + 64];
    x0.x = __expf(x0.x * s); x0.y = __expf(x0.y * s);
    x0.z = __expf(x0.z * s); x0.w = __expf(x0.w * s);
    x1.x = __expf(x1.x * s); x1.y = __expf(x1.y * s);
    x1.z = __expf(x1.z * s); x1.w = __expf(x1.w * s);
    Kr[lane] = x0; Kr[lane + 64] = x1;
    float acc = x0.x + x0.y + x0.z + x0.w + x1.x + x1.y + x1.z + x1.w;
#pragma unroll
    for (int off = 32; off; off >>= 1) acc += __shfl_down(acc, off);
    if (lane == 0) u[row] = INVN / acc;
  }
  grid.sync();

  // ---- Sinkhorn alternation ----
  for (int itn = 0;; ++itn) {
    // col pass: v[b,j] = INVN / sum_i K[b,i,j]*u[b,i]   (16 cols per block)
    {
      int b = blk >> 5, jb = (blk & 31) * 16;
      int c = t & 15, rg = t >> 4;
      const float* Kb = C + (size_t)b * 262144;
      const float* ub = u + b * 512;
      float acc = 0.f;
      for (int r = rg; r < 512; r += 16)
        acc += Kb[(size_t)r * 512 + jb + c] * ub[r];
      red[rg][c] = acc;
      __syncthreads();
      if (t < 16) {
        float tot = 0.f;
#pragma unroll
        for (int k = 0; k < 16; ++k) tot += red[k][t];
        v[b * 512 + jb + t] = INVN / tot;
      }
      __syncthreads();
    }
    grid.sync();
    if (itn == ITERS - 1) break;

    // row pass: u[b,i] = INVN / sum_j K[b,i,j]*v[b,j]
    for (int rr = 0; rr < 4; ++rr) {
      int row = blk * 16 + wv * 4 + rr;
      int b = row >> 9;
      const float4* Kr = (const float4*)(C + (size_t)row * 512);
      const float4* vb = (const float4*)(v + b * 512);
      float4 k0 = Kr[lane], k1 = Kr[lane + 64];
      float4 v0 = vb[lane], v1 = vb[lane + 64];
      float acc = k0.x * v0.x + k0.y * v0.y + k0.z * v0.z + k0.w * v0.w
                + k1.x * v1.x + k1.y * v1.y + k1.z * v1.z + k1.w * v1.w;
#pragma unroll
      for (int off = 32; off; off >>= 1) acc += __shfl_down(acc, off);
      if (lane == 0) u[row] = INVN / acc;
    }
    grid.sync();
  }

  // ---- Final: P = u[i] * K * v[j] in place (16 rows per block)
  for (int k2 = 0; k2 < 8; ++k2) {
    int idx = k2 * 256 + t;                 // 0..2047 f4 within block
    int rl = idx >> 7, c4 = idx & 127;
    int row = blk * 16 + rl;
    int b = row >> 9;
    float uu = u[row];
    float4 v4 = ((const float4*)(v + b * 512))[c4];
    float4* Kp = (float4*)(C + (size_t)row * 512);
    float4 kk = Kp[c4];
    kk.x *= uu * v4.x; kk.y *= uu * v4.y;
    kk.z *= uu * v4.z; kk.w *= uu * v4.w;
    Kp[c4] = kk;
  }
}

extern "C" void kernel_launch(void* const* d_in, const int* in_sizes, int n_in,
                              void* d_out, int out_size, void* d_ws, size_t ws_size,
                              hipStream_t stream) {
  const float* emb_in  = (const float*)d_in[0];
  const void*  maskp   = d_in[1];
  const float* emb_out = (const float*)d_in[2];
  const float* pad     = (const float*)d_in[3];
  const float* pos     = (const float*)d_in[4];
  const float* Win     = (const float*)d_in[5];
  const float* bin     = (const float*)d_in[6];
  const float* Wout    = (const float*)d_in[7];
  const float* bout    = (const float*)d_in[8];
  float* C = (float*)d_out;
  char* ws = (char*)d_ws;

  void* args[] = {(void*)&emb_in, (void*)&maskp, (void*)&emb_out, (void*)&pad,
                  (void*)&pos, (void*)&Win, (void*)&bin, (void*)&Wout,
                  (void*)&bout, (void*)&C, (void*)&ws};
  hipLaunchCooperativeKernel((const void*)sinkhorn_fused, dim3(256), dim3(256),
                             args, 0, stream);
}

// Round 3
// 279.417 us; speedup vs baseline: 1.9689x; 1.9689x over previous
//
#include <hip/hip_runtime.h>

#define EPS 1e-4f
#define ITERS 3
#define INVN (1.0f/512.0f)

// grid = 256 blocks x 256 threads; block blk -> batch b = blk&7 (XCD-affine),
// loc = blk>>3 (0..31), owns rows [loc*16, loc*16+16) of batch b.
//
// ws layout (bytes):
//   [0, 4096)        per-batch barrier slots: cnt @ 256*b, gen @ 256*b+128  (memset to 0 each launch)
//   [4096, 5120)     partsum [8][32] f32   (cost-matrix partial sums)
//   [8192, 532480)   parts   [8][32][512] f32  == alias == a [8][512][32] f32 (a dead before parts born)
//   [532480,1056768) bv      [8][512][32] f32

__device__ __forceinline__ void batch_barrier(int* cnt, int* gen) {
  __threadfence();                 // release: make this block's writes visible device-wide
  __syncthreads();
  if (threadIdx.x == 0) {
    int g = __hip_atomic_load(gen, __ATOMIC_RELAXED, __HIP_MEMORY_SCOPE_AGENT);
    int prev = __hip_atomic_fetch_add(cnt, 1, __ATOMIC_ACQ_REL, __HIP_MEMORY_SCOPE_AGENT);
    if (prev == 31) {              // last of the batch's 32 blocks
      __hip_atomic_store(cnt, 0, __ATOMIC_RELAXED, __HIP_MEMORY_SCOPE_AGENT);
      __hip_atomic_fetch_add(gen, 1, __ATOMIC_RELEASE, __HIP_MEMORY_SCOPE_AGENT);
    } else {
      while (__hip_atomic_load(gen, __ATOMIC_ACQUIRE, __HIP_MEMORY_SCOPE_AGENT) == g) {}
    }
  }
  __syncthreads();
  __threadfence();                 // acquire: invalidate stale cache lines before reading peers' data
}

__global__ void __launch_bounds__(256)
sinkhorn_one(const float* __restrict__ emb_in, const void* __restrict__ maskp,
             const float* __restrict__ emb_out, const float* __restrict__ pad,
             const float* __restrict__ pos, const float* __restrict__ Win,
             const float* __restrict__ bin, const float* __restrict__ Wout,
             const float* __restrict__ bout, float* __restrict__ P,
             char* __restrict__ ws) {
  const int t = threadIdx.x;
  const int blk = blockIdx.x;
  const int b = blk & 7, loc = blk >> 3;
  const int r0 = loc * 16;

  int* bcnt = (int*)(ws + 256 * b);
  int* bgen = (int*)(ws + 256 * b + 128);
  float* partsumG = (float*)(ws + 4096);
  float* partsG = (float*)(ws + 8192);
  float* aG = (float*)(ws + 8192);                   // alias of parts (disjoint lifetime)
  float* bvG = (float*)(ws + 8192 + 524288);

  __shared__ float K_sh[16][512];                    // C -> K, block-resident all phases (32 KB)
  __shared__ float colacc_sh[4][512];                // per-wave column partial slabs (8 KB)
  __shared__ float v_sh[512];
  __shared__ float rs[256];
  __shared__ int mv_sh[16];
  __shared__ unsigned dsh[2];

  // ---- Phase 0: mask element-size detect (block-local, first 4096 bytes) ----
  if (t < 2) dsh[t] = 0u;
  __syncthreads();
  {
    const unsigned char* mb = (const unsigned char*)maskp;
    unsigned orb = 0, orc = 0;
    for (int i = t * 16; i < t * 16 + 16; ++i) {
      unsigned val = mb[i];
      if (i & 3) orb |= val;              // nonzero only if 1-byte elements
      if ((i & 7) == 4) orc |= val;       // nonzero only if 4-byte elements
    }
    if (orb) atomicOr(&dsh[0], 1u);
    if (orc) atomicOr(&dsh[1], 1u);
  }
  __syncthreads();
  if (t < 16) {
    int g = b * 512 + r0 + t;
    int mv;
    if (dsh[0])      mv = ((const unsigned char*)maskp)[g];
    else if (dsh[1]) mv = ((const int*)maskp)[g];
    else             mv = (int)(((const long long*)maskp)[g] != 0);
    mv_sh[t] = mv;
  }
  __syncthreads();

  // ---- Phase 1: embed GEMMs for OWN 16 nodes ----
  // a[g][m] = (emb_out[g]+pos[n]) @ Wout[:,m] + bout[m]
  // bv[g][m] = (mask ? pad : emb_in[g]) @ Win[:,m] + bin[m]
  {
    int r = t >> 4, mh = t & 15;          // node r (0..15), m-pair (mh, mh+16)
    int n = r0 + r;
    int g = b * 512 + n;
    const float* eo = emb_out + (size_t)g * 256;
    const float* po = pos + (size_t)n * 256;
    const float* ib = mv_sh[r] ? pad : (emb_in + (size_t)g * 256);
    float a0 = bout[mh], a1 = bout[mh + 16];
    float b0 = bin[mh],  b1 = bin[mh + 16];
    for (int d = 0; d < 256; d += 4) {
      float4 e4 = *(const float4*)(eo + d);
      float4 p4 = *(const float4*)(po + d);
      float4 i4 = *(const float4*)(ib + d);
      float xs0 = e4.x + p4.x, xs1 = e4.y + p4.y, xs2 = e4.z + p4.z, xs3 = e4.w + p4.w;
      a0 = fmaf(xs0, Wout[(d+0)*32+mh], a0); a1 = fmaf(xs0, Wout[(d+0)*32+mh+16], a1);
      a0 = fmaf(xs1, Wout[(d+1)*32+mh], a0); a1 = fmaf(xs1, Wout[(d+1)*32+mh+16], a1);
      a0 = fmaf(xs2, Wout[(d+2)*32+mh], a0); a1 = fmaf(xs2, Wout[(d+2)*32+mh+16], a1);
      a0 = fmaf(xs3, Wout[(d+3)*32+mh], a0); a1 = fmaf(xs3, Wout[(d+3)*32+mh+16], a1);
      b0 = fmaf(i4.x, Win[(d+0)*32+mh], b0); b1 = fmaf(i4.x, Win[(d+0)*32+mh+16], b1);
      b0 = fmaf(i4.y, Win[(d+1)*32+mh], b0); b1 = fmaf(i4.y, Win[(d+1)*32+mh+16], b1);
      b0 = fmaf(i4.z, Win[(d+2)*32+mh], b0); b1 = fmaf(i4.z, Win[(d+2)*32+mh+16], b1);
      b0 = fmaf(i4.w, Win[(d+3)*32+mh], b0); b1 = fmaf(i4.w, Win[(d+3)*32+mh+16], b1);
    }
    aG [(size_t)g * 32 + mh] = a0;  aG [(size_t)g * 32 + mh + 16] = a1;
    bvG[(size_t)g * 32 + mh] = b0;  bvG[(size_t)g * 32 + mh + 16] = b1;
  }
  batch_barrier(bcnt, bgen);                         // bar 1: a, bv complete for batch

  // ---- Phase 2: C rows (own 16) into LDS + cost partial sum ----
  {
    float bva[32], bvb[32];                          // two owned columns: j0=t, j1=t+256
#pragma unroll
    for (int q = 0; q < 8; ++q) {
      float4 f = *(const float4*)(bvG + (size_t)(b * 512 + t) * 32 + q * 4);
      bva[q*4+0] = f.x; bva[q*4+1] = f.y; bva[q*4+2] = f.z; bva[q*4+3] = f.w;
      float4 h = *(const float4*)(bvG + (size_t)(b * 512 + t + 256) * 32 + q * 4);
      bvb[q*4+0] = h.x; bvb[q*4+1] = h.y; bvb[q*4+2] = h.z; bvb[q*4+3] = h.w;
    }
    const float* arow0 = aG + (size_t)(b * 512 + r0) * 32;
    float csum = 0.f;
    for (int r = 0; r < 16; ++r) {
      const float* ar = arow0 + r * 32;              // uniform address -> scalar loads
      float c0 = 0.f, c1 = 0.f;
#pragma unroll
      for (int m = 0; m < 32; ++m) {
        float av = ar[m];
        c0 += fabsf(av - bva[m]);
        c1 += fabsf(av - bvb[m]);
      }
      K_sh[r][t] = c0; K_sh[r][t + 256] = c1;
      csum += c0 + c1;
    }
    rs[t] = csum;
    __syncthreads();
    for (int off = 128; off; off >>= 1) {
      if (t < off) rs[t] += rs[t + off];
      __syncthreads();
    }
    if (t == 0) partsumG[b * 32 + loc] = rs[0];
  }
  batch_barrier(bcnt, bgen);                         // bar 2: all cost partials ready

  // ---- invES (computed redundantly, deterministically, by every thread) ----
  float sv;
  {
    const float* ps = partsumG + b * 32;
    float S = 0.f;
#pragma unroll
    for (int k = 0; k < 32; ++k) S += ps[k];
    sv = -1.0f / (EPS * S);
  }

  const int w = t >> 6, lane = t & 63;               // wave w owns rows w*4..w*4+3
  float u_last[4];
  float* partrow = partsG + (size_t)(b * 32 + loc) * 512;

  // ---- Pass 1: K = exp(C*sv) fused with row update (v == 1) + column partials ----
  {
    float colacc[8] = {0,0,0,0,0,0,0,0};
#pragma unroll
    for (int rr = 0; rr < 4; ++rr) {
      int r = w * 4 + rr;
      float4 c0 = *(float4*)&K_sh[r][lane * 8];
      float4 c1 = *(float4*)&K_sh[r][lane * 8 + 4];
      float kv[8];
      kv[0] = __expf(c0.x * sv); kv[1] = __expf(c0.y * sv);
      kv[2] = __expf(c0.z * sv); kv[3] = __expf(c0.w * sv);
      kv[4] = __expf(c1.x * sv); kv[5] = __expf(c1.y * sv);
      kv[6] = __expf(c1.z * sv); kv[7] = __expf(c1.w * sv);
      *(float4*)&K_sh[r][lane * 8]     = make_float4(kv[0], kv[1], kv[2], kv[3]);
      *(float4*)&K_sh[r][lane * 8 + 4] = make_float4(kv[4], kv[5], kv[6], kv[7]);
      float s = kv[0]+kv[1]+kv[2]+kv[3]+kv[4]+kv[5]+kv[6]+kv[7];
#pragma unroll
      for (int off = 1; off < 64; off <<= 1) s += __shfl_xor(s, off);
      float uu = INVN / s;
      u_last[rr] = uu;
#pragma unroll
      for (int q = 0; q < 8; ++q) colacc[q] = fmaf(kv[q], uu, colacc[q]);
    }
    *(float4*)&colacc_sh[w][lane * 8]     = make_float4(colacc[0], colacc[1], colacc[2], colacc[3]);
    *(float4*)&colacc_sh[w][lane * 8 + 4] = make_float4(colacc[4], colacc[5], colacc[6], colacc[7]);
    __syncthreads();
    partrow[t]       = colacc_sh[0][t]       + colacc_sh[1][t]       + colacc_sh[2][t]       + colacc_sh[3][t];
    partrow[t + 256] = colacc_sh[0][t + 256] + colacc_sh[1][t + 256] + colacc_sh[2][t + 256] + colacc_sh[3][t + 256];
  }
  batch_barrier(bcnt, bgen);                         // bar 3: column partials (iter 1) ready

  // ---- Iterations 2..ITERS: v-recompute + row update + column partials ----
  for (int it = 1; it < ITERS; ++it) {
    {
      const float* pb = partsG + (size_t)b * 32 * 512;
      float s0 = 0.f, s1 = 0.f;
#pragma unroll
      for (int k = 0; k < 32; ++k) {
        s0 += pb[k * 512 + t];
        s1 += pb[k * 512 + t + 256];
      }
      v_sh[t] = INVN / s0;
      v_sh[t + 256] = INVN / s1;
    }
    __syncthreads();
    float vreg[8];
    {
      float4 v0 = *(float4*)&v_sh[lane * 8];
      float4 v1 = *(float4*)&v_sh[lane * 8 + 4];
      vreg[0]=v0.x; vreg[1]=v0.y; vreg[2]=v0.z; vreg[3]=v0.w;
      vreg[4]=v1.x; vreg[5]=v1.y; vreg[6]=v1.z; vreg[7]=v1.w;
    }
    float colacc[8] = {0,0,0,0,0,0,0,0};
#pragma unroll
    for (int rr = 0; rr < 4; ++rr) {
      int r = w * 4 + rr;
      float4 k0 = *(float4*)&K_sh[r][lane * 8];
      float4 k1 = *(float4*)&K_sh[r][lane * 8 + 4];
      float kv[8] = {k0.x, k0.y, k0.z, k0.w, k1.x, k1.y, k1.z, k1.w};
      float s = 0.f;
#pragma unroll
      for (int q = 0; q < 8; ++q) s = fmaf(kv[q], vreg[q], s);
#pragma unroll
      for (int off = 1; off < 64; off <<= 1) s += __shfl_xor(s, off);
      float uu = INVN / s;
      u_last[rr] = uu;
#pragma unroll
      for (int q = 0; q < 8; ++q) colacc[q] = fmaf(kv[q], uu, colacc[q]);
    }
    *(float4*)&colacc_sh[w][lane * 8]     = make_float4(colacc[0], colacc[1], colacc[2], colacc[3]);
    *(float4*)&colacc_sh[w][lane * 8 + 4] = make_float4(colacc[4], colacc[5], colacc[6], colacc[7]);
    __syncthreads();
    partrow[t]       = colacc_sh[0][t]       + colacc_sh[1][t]       + colacc_sh[2][t]       + colacc_sh[3][t];
    partrow[t + 256] = colacc_sh[0][t + 256] + colacc_sh[1][t + 256] + colacc_sh[2][t + 256] + colacc_sh[3][t + 256];
    batch_barrier(bcnt, bgen);                       // bar 4,5: partials for this iter ready
  }

  // ---- Final: v from last partials; P = u * K * v ----
  {
    const float* pb = partsG + (size_t)b * 32 * 512;
    float s0 = 0.f, s1 = 0.f;
#pragma unroll
    for (int k = 0; k < 32; ++k) {
      s0 += pb[k * 512 + t];
      s1 += pb[k * 512 + t + 256];
    }
    v_sh[t] = INVN / s0;
    v_sh[t + 256] = INVN / s1;
  }
  __syncthreads();
  {
    float4 v0 = *(float4*)&v_sh[lane * 8];
    float4 v1 = *(float4*)&v_sh[lane * 8 + 4];
#pragma unroll
    for (int rr = 0; rr < 4; ++rr) {
      int r = w * 4 + rr;
      float uu = u_last[rr];
      float4 k0 = *(float4*)&K_sh[r][lane * 8];
      float4 k1 = *(float4*)&K_sh[r][lane * 8 + 4];
      float4 o0 = make_float4(uu * k0.x * v0.x, uu * k0.y * v0.y,
                              uu * k0.z * v0.z, uu * k0.w * v0.w);
      float4 o1 = make_float4(uu * k1.x * v1.x, uu * k1.y * v1.y,
                              uu * k1.z * v1.z, uu * k1.w * v1.w);
      float* Prow = P + (size_t)(b * 512 + r0 + r) * 512;
      *(float4*)(Prow + lane * 8)     = o0;
      *(float4*)(Prow + lane * 8 + 4) = o1;
    }
  }
}

extern "C" void kernel_launch(void* const* d_in, const int* in_sizes, int n_in,
                              void* d_out, int out_size, void* d_ws, size_t ws_size,
                              hipStream_t stream) {
  const float* emb_in  = (const float*)d_in[0];
  const void*  maskp   = d_in[1];
  const float* emb_out = (const float*)d_in[2];
  const float* pad     = (const float*)d_in[3];
  const float* pos     = (const float*)d_in[4];
  const float* Win     = (const float*)d_in[5];
  const float* bin     = (const float*)d_in[6];
  const float* Wout    = (const float*)d_in[7];
  const float* bout    = (const float*)d_in[8];
  float* P = (float*)d_out;
  char* ws = (char*)d_ws;

  hipMemsetAsync(ws, 0, 4096, stream);               // zero barrier counters each launch

  void* args[] = {(void*)&emb_in, (void*)&maskp, (void*)&emb_out, (void*)&pad,
                  (void*)&pos, (void*)&Win, (void*)&bin, (void*)&Wout,
                  (void*)&bout, (void*)&P, (void*)&ws};
  hipLaunchCooperativeKernel((const void*)sinkhorn_one, dim3(256), dim3(256),
                             args, 0, stream);
}

// Round 4
// 89.979 us; speedup vs baseline: 6.1142x; 3.1054x over previous
//
#include <hip/hip_runtime.h>

#define EPS 1e-4f
#define ITERS 3
#define INVN (1.0f/512.0f)

// grid = 256 blocks x 512 threads; block blk -> batch b = blk&7, loc = blk>>3,
// owns rows [loc*16, loc*16+16) of batch b's 512x512 K (LDS-resident).
//
// ws layout (bytes):
//   [0, 2048)         barrier slots, batch b at 256*b: cnt_i @ +4*i, flag_i @ +128+4*i  (i<8)
//                     one-shot per barrier instance; memset to 0 each launch
//   [4096, 5120)      partsum [8][32] f32
//   [8192, 532480)    parts   [8][32][512] f32  (column partial sums)
//   [532480, 1056768) bv      [4096][32] f32
//
// Barrier: fence-minimal. Per-poll ACQUIRE (round 2/3's bug) invalidated the
// whole XCD L2 every spin iteration -> ~250us idle. Now: one wbl2 on arrive
// (release), relaxed LLC spin, one buffer_inv on exit (acquire).

__device__ __forceinline__ void batch_barrier(int* cnt, int* flag) {
  asm volatile("s_waitcnt vmcnt(0)" ::: "memory");   // drain this wave's stores to L2
  __syncthreads();                                   // all waves of block drained
  if (threadIdx.x == 0) {
    __builtin_amdgcn_fence(__ATOMIC_RELEASE, "agent");  // writeback block's dirty L2 (small)
    int prev = __hip_atomic_fetch_add(cnt, 1, __ATOMIC_RELAXED, __HIP_MEMORY_SCOPE_AGENT);
    if (prev == 31) {                                // last of 32 blocks: all data at LLC
      __builtin_amdgcn_fence(__ATOMIC_ACQUIRE, "agent");
      __hip_atomic_store(flag, 1, __ATOMIC_RELAXED, __HIP_MEMORY_SCOPE_AGENT);
    } else {
      int n = 0;
      while (__hip_atomic_load(flag, __ATOMIC_RELAXED, __HIP_MEMORY_SCOPE_AGENT) == 0) {
        if ((++n & 1023) == 0)                       // insurance vs cached spin line
          (void)__hip_atomic_load(flag, __ATOMIC_ACQUIRE, __HIP_MEMORY_SCOPE_AGENT);
      }
      __builtin_amdgcn_fence(__ATOMIC_ACQUIRE, "agent"); // one L1+L2 inv for the block
    }
  }
  __syncthreads();
}

__global__ void __launch_bounds__(512)
sinkhorn_one(const float* __restrict__ emb_in, const void* __restrict__ maskp,
             const float* __restrict__ emb_out, const float* __restrict__ pad,
             const float* __restrict__ pos, const float* __restrict__ Win,
             const float* __restrict__ bin, const float* __restrict__ Wout,
             const float* __restrict__ bout, float* __restrict__ P,
             char* __restrict__ ws) {
  const int t = threadIdx.x;
  const int blk = blockIdx.x;
  const int b = blk & 7, loc = blk >> 3;
  const int r0 = loc * 16;
  const int w = t >> 6, lane = t & 63;

  int* cnts  = (int*)(ws + 256 * b);           // cnts[i], i<8
  int* flags = (int*)(ws + 256 * b + 128);     // flags[i]
  float* partsumG = (float*)(ws + 4096);
  float* partsG   = (float*)(ws + 8192);
  float* bvG      = (float*)(ws + 532480);

  __shared__ float K_sh[16][512];              // 32 KB, block-resident C->K->P
  __shared__ float colacc_sh[8][512];          // 16 KB per-wave column partials
  __shared__ float a_sh[16][32];               // own a-rows (never leaves block)
  __shared__ float v_sh[512];
  __shared__ float red_sh[8];
  __shared__ float sv_sh;
  __shared__ int mv_sh[16];
  __shared__ unsigned dsh[2];

  // ---- Phase 0: mask element-size detect (first 4096 bytes; safe for all dtypes) ----
  if (t < 2) dsh[t] = 0u;
  __syncthreads();
  if (t < 256) {
    const unsigned char* mb = (const unsigned char*)maskp;
    unsigned orb = 0, orc = 0;
    for (int i = t * 16; i < t * 16 + 16; ++i) {
      unsigned val = mb[i];
      if (i & 3) orb |= val;                   // nonzero only if 1-byte elements
      if ((i & 7) == 4) orc |= val;            // nonzero only if 4-byte elements
    }
    if (orb) atomicOr(&dsh[0], 1u);
    if (orc) atomicOr(&dsh[1], 1u);
  }
  __syncthreads();
  if (t < 16) {
    int g = b * 512 + r0 + t;
    int mv;
    if (dsh[0])      mv = ((const unsigned char*)maskp)[g];
    else if (dsh[1]) mv = ((const int*)maskp)[g];
    else             mv = (int)(((const long long*)maskp)[g] != 0);
    mv_sh[t] = mv;
  }
  __syncthreads();

  // ---- Phase 1: embed GEMVs, one (node, m) per thread ----
  {
    const int r = t >> 5, m = t & 31;
    const int node = r0 + r;
    const int g = b * 512 + node;
    const float* eo = emb_out + (size_t)g * 256;
    const float* po = pos + (size_t)node * 256;
    const float* ei = mv_sh[r] ? pad : (emb_in + (size_t)g * 256);
    float aa = bout[m], bb = bin[m];
    for (int d = 0; d < 256; d += 4) {
      float4 e4 = *(const float4*)(eo + d);
      float4 p4 = *(const float4*)(po + d);
      float4 i4 = *(const float4*)(ei + d);
      aa = fmaf(e4.x + p4.x, Wout[(d + 0) * 32 + m], aa);
      aa = fmaf(e4.y + p4.y, Wout[(d + 1) * 32 + m], aa);
      aa = fmaf(e4.z + p4.z, Wout[(d + 2) * 32 + m], aa);
      aa = fmaf(e4.w + p4.w, Wout[(d + 3) * 32 + m], aa);
      bb = fmaf(i4.x, Win[(d + 0) * 32 + m], bb);
      bb = fmaf(i4.y, Win[(d + 1) * 32 + m], bb);
      bb = fmaf(i4.z, Win[(d + 2) * 32 + m], bb);
      bb = fmaf(i4.w, Win[(d + 3) * 32 + m], bb);
    }
    a_sh[r][m] = aa;
    bvG[(size_t)g * 32 + m] = bb;
  }
  batch_barrier(&cnts[0], &flags[0]);          // bv complete for batch

  // ---- Phase 2: C tile (16 rows x 512 cols), one column per thread ----
  {
    float bva[32];
    const float4* bj = (const float4*)(bvG + ((size_t)(b * 512) + t) * 32);
#pragma unroll
    for (int q = 0; q < 8; ++q) {
      float4 f = bj[q];
      bva[q * 4 + 0] = f.x; bva[q * 4 + 1] = f.y;
      bva[q * 4 + 2] = f.z; bva[q * 4 + 3] = f.w;
    }
    float csum = 0.f;
    for (int r = 0; r < 16; ++r) {
      const float4* ar4 = (const float4*)&a_sh[r][0];   // broadcast reads
      float c0 = 0.f;
#pragma unroll
      for (int q = 0; q < 8; ++q) {
        float4 av = ar4[q];
        c0 += fabsf(av.x - bva[q * 4 + 0]) + fabsf(av.y - bva[q * 4 + 1])
            + fabsf(av.z - bva[q * 4 + 2]) + fabsf(av.w - bva[q * 4 + 3]);
      }
      K_sh[r][t] = c0;
      csum += c0;
    }
#pragma unroll
    for (int off = 1; off < 64; off <<= 1) csum += __shfl_xor(csum, off);
    if (lane == 0) red_sh[w] = csum;
    __syncthreads();
    if (t == 0) {
      float s = 0.f;
#pragma unroll
      for (int k = 0; k < 8; ++k) s += red_sh[k];
      partsumG[b * 32 + loc] = s;
    }
  }
  batch_barrier(&cnts[1], &flags[1]);          // cost partials ready

  // ---- sv = -1/(EPS*S), computed by wave 0, broadcast via LDS ----
  if (t < 64) {
    float pv = (t < 32) ? partsumG[b * 32 + t] : 0.f;
#pragma unroll
    for (int off = 1; off < 64; off <<= 1) pv += __shfl_xor(pv, off);
    if (t == 0) sv_sh = -1.0f / (EPS * pv);
  }
  __syncthreads();
  const float sv = sv_sh;

  float u_last[2];
  float* partrow = partsG + ((size_t)(b * 32) + loc) * 512;

  // ---- Pass 1: K = exp(C*sv) fused with row update (v==1) + column partials ----
  {
    float colacc[8] = {0, 0, 0, 0, 0, 0, 0, 0};
#pragma unroll
    for (int rr = 0; rr < 2; ++rr) {
      int r = 2 * w + rr;
      float4 c0 = *(float4*)&K_sh[r][4 * lane];
      float4 c1 = *(float4*)&K_sh[r][256 + 4 * lane];
      float kv[8];
      kv[0] = __expf(c0.x * sv); kv[1] = __expf(c0.y * sv);
      kv[2] = __expf(c0.z * sv); kv[3] = __expf(c0.w * sv);
      kv[4] = __expf(c1.x * sv); kv[5] = __expf(c1.y * sv);
      kv[6] = __expf(c1.z * sv); kv[7] = __expf(c1.w * sv);
      *(float4*)&K_sh[r][4 * lane]       = make_float4(kv[0], kv[1], kv[2], kv[3]);
      *(float4*)&K_sh[r][256 + 4 * lane] = make_float4(kv[4], kv[5], kv[6], kv[7]);
      float s = kv[0] + kv[1] + kv[2] + kv[3] + kv[4] + kv[5] + kv[6] + kv[7];
#pragma unroll
      for (int off = 1; off < 64; off <<= 1) s += __shfl_xor(s, off);
      float uu = INVN / s;
      u_last[rr] = uu;
#pragma unroll
      for (int q = 0; q < 8; ++q) colacc[q] = fmaf(kv[q], uu, colacc[q]);
    }
    *(float4*)&colacc_sh[w][4 * lane]       = make_float4(colacc[0], colacc[1], colacc[2], colacc[3]);
    *(float4*)&colacc_sh[w][256 + 4 * lane] = make_float4(colacc[4], colacc[5], colacc[6], colacc[7]);
    __syncthreads();
    float s0 = 0.f;
#pragma unroll
    for (int k = 0; k < 8; ++k) s0 += colacc_sh[k][t];
    partrow[t] = s0;
  }
  batch_barrier(&cnts[2], &flags[2]);          // iter-1 column partials ready

  // ---- Iterations 2..ITERS ----
  for (int it = 1; it < ITERS; ++it) {
    {
      const float* pb = partsG + (size_t)b * 32 * 512;
      float s = 0.f;
#pragma unroll
      for (int k = 0; k < 32; ++k) s += pb[k * 512 + t];
      v_sh[t] = INVN / s;
    }
    __syncthreads();
    float4 v0 = *(float4*)&v_sh[4 * lane];
    float4 v1 = *(float4*)&v_sh[256 + 4 * lane];
    float vr[8] = {v0.x, v0.y, v0.z, v0.w, v1.x, v1.y, v1.z, v1.w};
    float colacc[8] = {0, 0, 0, 0, 0, 0, 0, 0};
#pragma unroll
    for (int rr = 0; rr < 2; ++rr) {
      int r = 2 * w + rr;
      float4 k0 = *(float4*)&K_sh[r][4 * lane];
      float4 k1 = *(float4*)&K_sh[r][256 + 4 * lane];
      float kv[8] = {k0.x, k0.y, k0.z, k0.w, k1.x, k1.y, k1.z, k1.w};
      float s = 0.f;
#pragma unroll
      for (int q = 0; q < 8; ++q) s = fmaf(kv[q], vr[q], s);
#pragma unroll
      for (int off = 1; off < 64; off <<= 1) s += __shfl_xor(s, off);
      float uu = INVN / s;
      u_last[rr] = uu;
#pragma unroll
      for (int q = 0; q < 8; ++q) colacc[q] = fmaf(kv[q], uu, colacc[q]);
    }
    __syncthreads();   // v_sh reads done before colacc_sh overwrite? (separate buffers; this orders K_sh reuse anyway)
    *(float4*)&colacc_sh[w][4 * lane]       = make_float4(colacc[0], colacc[1], colacc[2], colacc[3]);
    *(float4*)&colacc_sh[w][256 + 4 * lane] = make_float4(colacc[4], colacc[5], colacc[6], colacc[7]);
    __syncthreads();
    float s0 = 0.f;
#pragma unroll
    for (int k = 0; k < 8; ++k) s0 += colacc_sh[k][t];
    partrow[t] = s0;
    batch_barrier(&cnts[2 + it], &flags[2 + it]);
  }

  // ---- Final: v from last partials; P = u * K * v ----
  {
    const float* pb = partsG + (size_t)b * 32 * 512;
    float s = 0.f;
#pragma unroll
    for (int k = 0; k < 32; ++k) s += pb[k * 512 + t];
    v_sh[t] = INVN / s;
  }
  __syncthreads();
  {
    float4 v0 = *(float4*)&v_sh[4 * lane];
    float4 v1 = *(float4*)&v_sh[256 + 4 * lane];
#pragma unroll
    for (int rr = 0; rr < 2; ++rr) {
      int r = 2 * w + rr;
      float uu = u_last[rr];
      float4 k0 = *(float4*)&K_sh[r][4 * lane];
      float4 k1 = *(float4*)&K_sh[r][256 + 4 * lane];
      float4 o0 = make_float4(uu * k0.x * v0.x, uu * k0.y * v0.y,
                              uu * k0.z * v0.z, uu * k0.w * v0.w);
      float4 o1 = make_float4(uu * k1.x * v1.x, uu * k1.y * v1.y,
                              uu * k1.z * v1.z, uu * k1.w * v1.w);
      float* Prow = P + ((size_t)(b * 512) + r0 + r) * 512;
      *(float4*)(Prow + 4 * lane)       = o0;
      *(float4*)(Prow + 256 + 4 * lane) = o1;
    }
  }
}

extern "C" void kernel_launch(void* const* d_in, const int* in_sizes, int n_in,
                              void* d_out, int out_size, void* d_ws, size_t ws_size,
                              hipStream_t stream) {
  const float* emb_in  = (const float*)d_in[0];
  const void*  maskp   = d_in[1];
  const float* emb_out = (const float*)d_in[2];
  const float* pad     = (const float*)d_in[3];
  const float* pos     = (const float*)d_in[4];
  const float* Win     = (const float*)d_in[5];
  const float* bin     = (const float*)d_in[6];
  const float* Wout    = (const float*)d_in[7];
  const float* bout    = (const float*)d_in[8];
  float* P = (float*)d_out;
  char* ws = (char*)d_ws;

  hipMemsetAsync(ws, 0, 4096, stream);         // zero one-shot barrier slots

  void* args[] = {(void*)&emb_in, (void*)&maskp, (void*)&emb_out, (void*)&pad,
                  (void*)&pos, (void*)&Win, (void*)&bin, (void*)&Wout,
                  (void*)&bout, (void*)&P, (void*)&ws};
  hipLaunchCooperativeKernel((const void*)sinkhorn_one, dim3(256), dim3(512),
                             args, 0, stream);
}

// Round 5
// 74.398 us; speedup vs baseline: 7.3947x; 1.2094x over previous
//
#include <hip/hip_runtime.h>

#define EPS 1e-4f
#define ITERS 3
#define INVN (1.0f/512.0f)

// grid = 256 blocks x 512 threads; block blk -> batch b = blk&7, loc = blk>>3,
// owns rows [loc*16, loc*16+16) of batch b's 512x512 K (LDS-resident).
//
// Cross-block coherence: ALL shared arrays (bv, partsum, parts) are accessed
// with explicit sc0 sc1 global ops (write-through to LLC / load from LLC,
// bypassing the non-coherent per-XCD L2s). Barrier is fence-free: vmcnt(0)
// drains the write-through stores, then relaxed agent atomics on one-shot
// cnt/flag slots. No buffer_wbl2 / buffer_inv -> read-only inputs stay cached.
//
// ws layout (bytes):
//   [0, 2048)         barrier slots, batch b at 256*b: cnt_i @ +4*i, flag_i @ +128+4*i (i<8)
//                     one-shot; memset to 0 each launch
//   [4096, 5120)      partsum [8][32] f32
//   [8192, 532480)    parts   [8][32][512] f32  (column partial sums)
//   [532480, 1056768) bv      [4096][32] f32

__device__ __forceinline__ void store_f32_cg(float* p, float v) {
  asm volatile("global_store_dword %0, %1, off sc0 sc1" :: "v"(p), "v"(v) : "memory");
}

__device__ __forceinline__ float load_f32_cg(const float* p) {
  float r;
  asm volatile("global_load_dword %0, %1, off sc0 sc1\n\t"
               "s_waitcnt vmcnt(0)"
               : "=v"(r) : "v"(p) : "memory");
  return r;
}

// 8 contiguous float4 (32 floats) from LLC, one wait.
__device__ __forceinline__ void load8x4_cg(const float* p, float4* o) {
  asm volatile(
      "global_load_dwordx4 %0, %8, off sc0 sc1\n\t"
      "global_load_dwordx4 %1, %8, off offset:16 sc0 sc1\n\t"
      "global_load_dwordx4 %2, %8, off offset:32 sc0 sc1\n\t"
      "global_load_dwordx4 %3, %8, off offset:48 sc0 sc1\n\t"
      "global_load_dwordx4 %4, %8, off offset:64 sc0 sc1\n\t"
      "global_load_dwordx4 %5, %8, off offset:80 sc0 sc1\n\t"
      "global_load_dwordx4 %6, %8, off offset:96 sc0 sc1\n\t"
      "global_load_dwordx4 %7, %8, off offset:112 sc0 sc1\n\t"
      "s_waitcnt vmcnt(0)"
      : "=&v"(o[0]), "=&v"(o[1]), "=&v"(o[2]), "=&v"(o[3]),
        "=&v"(o[4]), "=&v"(o[5]), "=&v"(o[6]), "=&v"(o[7])
      : "v"(p)
      : "memory");
}

// 8 float4 at 2048-byte stride (k-slices), one wait. p1 = base+4096B, p2 = base+12288B.
__device__ __forceinline__ void load8x4_s2k_cg(const float* p1, const float* p2, float4* o) {
  asm volatile(
      "global_load_dwordx4 %0, %8, off offset:-4096 sc0 sc1\n\t"
      "global_load_dwordx4 %1, %8, off offset:-2048 sc0 sc1\n\t"
      "global_load_dwordx4 %2, %8, off sc0 sc1\n\t"
      "global_load_dwordx4 %3, %8, off offset:2048 sc0 sc1\n\t"
      "global_load_dwordx4 %4, %9, off offset:-4096 sc0 sc1\n\t"
      "global_load_dwordx4 %5, %9, off offset:-2048 sc0 sc1\n\t"
      "global_load_dwordx4 %6, %9, off sc0 sc1\n\t"
      "global_load_dwordx4 %7, %9, off offset:2048 sc0 sc1\n\t"
      "s_waitcnt vmcnt(0)"
      : "=&v"(o[0]), "=&v"(o[1]), "=&v"(o[2]), "=&v"(o[3]),
        "=&v"(o[4]), "=&v"(o[5]), "=&v"(o[6]), "=&v"(o[7])
      : "v"(p1), "v"(p2)
      : "memory");
}

__device__ __forceinline__ void batch_barrier(int* cnt, int* flag) {
  asm volatile("s_waitcnt vmcnt(0)" ::: "memory");   // drain write-through stores to LLC
  __syncthreads();
  if (threadIdx.x == 0) {
    int prev = __hip_atomic_fetch_add(cnt, 1, __ATOMIC_RELAXED, __HIP_MEMORY_SCOPE_AGENT);
    if (prev == 31) {
      __hip_atomic_store(flag, 1, __ATOMIC_RELAXED, __HIP_MEMORY_SCOPE_AGENT);
    } else {
      while (__hip_atomic_load(flag, __ATOMIC_RELAXED, __HIP_MEMORY_SCOPE_AGENT) == 0) {}
    }
  }
  __syncthreads();
}

__global__ void __launch_bounds__(512)
sinkhorn_one(const float* __restrict__ emb_in, const void* __restrict__ maskp,
             const float* __restrict__ emb_out, const float* __restrict__ pad,
             const float* __restrict__ pos, const float* __restrict__ Win,
             const float* __restrict__ bin, const float* __restrict__ Wout,
             const float* __restrict__ bout, float* __restrict__ P,
             char* __restrict__ ws) {
  const int t = threadIdx.x;
  const int blk = blockIdx.x;
  const int b = blk & 7, loc = blk >> 3;
  const int r0 = loc * 16;
  const int w = t >> 6, lane = t & 63;

  int* cnts  = (int*)(ws + 256 * b);
  int* flags = (int*)(ws + 256 * b + 128);
  float* partsumG = (float*)(ws + 4096);
  float* partsG   = (float*)(ws + 8192);
  float* bvG      = (float*)(ws + 532480);

  __shared__ float K_sh[16][512];        // 32 KB: C -> K, block-resident
  __shared__ float scratch_sh[8][512];   // 16 KB: colacc rows 0..7 / vred rows 0..3
  __shared__ float v_sh[512];
  __shared__ float a_sh[16][32];
  __shared__ float red_sh[8];
  __shared__ float sv_sh;
  __shared__ int mv_sh[16];
  __shared__ unsigned dsh[2];

  // ---- Phase 0: mask element-size detect (first 4096 bytes) ----
  if (t < 2) dsh[t] = 0u;
  __syncthreads();
  if (t < 256) {
    const unsigned char* mb = (const unsigned char*)maskp;
    unsigned orb = 0, orc = 0;
    for (int i = t * 16; i < t * 16 + 16; ++i) {
      unsigned val = mb[i];
      if (i & 3) orb |= val;             // nonzero only if 1-byte elements
      if ((i & 7) == 4) orc |= val;      // nonzero only if 4-byte elements
    }
    if (orb) atomicOr(&dsh[0], 1u);
    if (orc) atomicOr(&dsh[1], 1u);
  }
  __syncthreads();
  if (t < 16) {
    int g = b * 512 + r0 + t;
    int mv;
    if (dsh[0])      mv = ((const unsigned char*)maskp)[g];
    else if (dsh[1]) mv = ((const int*)maskp)[g];
    else             mv = (int)(((const long long*)maskp)[g] != 0);
    mv_sh[t] = mv;
  }
  __syncthreads();

  // ---- Phase 1: embed GEMVs, one (node, m) per thread ----
  {
    const int r = t >> 5, m = t & 31;
    const int node = r0 + r;
    const int g = b * 512 + node;
    const float* eo = emb_out + (size_t)g * 256;
    const float* po = pos + (size_t)node * 256;
    const float* ei = mv_sh[r] ? pad : (emb_in + (size_t)g * 256);
    float aa = bout[m], bb = bin[m];
    for (int d = 0; d < 256; d += 4) {
      float4 e4 = *(const float4*)(eo + d);
      float4 p4 = *(const float4*)(po + d);
      float4 i4 = *(const float4*)(ei + d);
      aa = fmaf(e4.x + p4.x, Wout[(d + 0) * 32 + m], aa);
      aa = fmaf(e4.y + p4.y, Wout[(d + 1) * 32 + m], aa);
      aa = fmaf(e4.z + p4.z, Wout[(d + 2) * 32 + m], aa);
      aa = fmaf(e4.w + p4.w, Wout[(d + 3) * 32 + m], aa);
      bb = fmaf(i4.x, Win[(d + 0) * 32 + m], bb);
      bb = fmaf(i4.y, Win[(d + 1) * 32 + m], bb);
      bb = fmaf(i4.z, Win[(d + 2) * 32 + m], bb);
      bb = fmaf(i4.w, Win[(d + 3) * 32 + m], bb);
    }
    a_sh[r][m] = aa;
    store_f32_cg(bvG + (size_t)g * 32 + m, bb);    // coherent through LLC
  }
  batch_barrier(&cnts[0], &flags[0]);              // bv complete for batch

  // ---- Phase 2: C tile (16 rows x 512 cols), one column per thread ----
  {
    float4 bq[8];
    load8x4_cg(bvG + ((size_t)(b * 512) + t) * 32, bq);
    float bva[32];
#pragma unroll
    for (int q = 0; q < 8; ++q) {
      bva[q * 4 + 0] = bq[q].x; bva[q * 4 + 1] = bq[q].y;
      bva[q * 4 + 2] = bq[q].z; bva[q * 4 + 3] = bq[q].w;
    }
    float csum = 0.f;
    for (int r = 0; r < 16; ++r) {
      const float4* ar4 = (const float4*)&a_sh[r][0];   // LDS broadcast reads
      float c0 = 0.f;
#pragma unroll
      for (int q = 0; q < 8; ++q) {
        float4 av = ar4[q];
        c0 += fabsf(av.x - bva[q * 4 + 0]) + fabsf(av.y - bva[q * 4 + 1])
            + fabsf(av.z - bva[q * 4 + 2]) + fabsf(av.w - bva[q * 4 + 3]);
      }
      K_sh[r][t] = c0;
      csum += c0;
    }
#pragma unroll
    for (int off = 1; off < 64; off <<= 1) csum += __shfl_xor(csum, off);
    if (lane == 0) red_sh[w] = csum;
    __syncthreads();
    if (t == 0) {
      float s = 0.f;
#pragma unroll
      for (int k = 0; k < 8; ++k) s += red_sh[k];
      store_f32_cg(partsumG + b * 32 + loc, s);
    }
  }
  batch_barrier(&cnts[1], &flags[1]);              // cost partials ready

  // ---- sv = -1/(EPS*S) ----
  if (t < 64) {
    float pv = (t < 32) ? load_f32_cg(partsumG + b * 32 + t) : 0.f;
#pragma unroll
    for (int off = 1; off < 64; off <<= 1) pv += __shfl_xor(pv, off);
    if (t == 0) sv_sh = -1.0f / (EPS * pv);
  }
  __syncthreads();
  const float sv = sv_sh;

  float u_last[2];
  float* partrow = partsG + ((size_t)(b * 32) + loc) * 512;
  const float* parts_b = partsG + (size_t)b * 32 * 512;
  const int w2 = t >> 7, idx = t & 127;
  const float* vp1 = parts_b + (size_t)(w2 * 8) * 512 + idx * 4 + 1024;  // +4096 B
  const float* vp2 = vp1 + 2048;                                         // +12288 B

  // ---- Pass 1: K = exp(C*sv) fused row update (v==1) + column partials ----
  {
    float colacc[8] = {0, 0, 0, 0, 0, 0, 0, 0};
#pragma unroll
    for (int rr = 0; rr < 2; ++rr) {
      int r = 2 * w + rr;
      float4 c0 = *(float4*)&K_sh[r][4 * lane];
      float4 c1 = *(float4*)&K_sh[r][256 + 4 * lane];
      float kv[8];
      kv[0] = __expf(c0.x * sv); kv[1] = __expf(c0.y * sv);
      kv[2] = __expf(c0.z * sv); kv[3] = __expf(c0.w * sv);
      kv[4] = __expf(c1.x * sv); kv[5] = __expf(c1.y * sv);
      kv[6] = __expf(c1.z * sv); kv[7] = __expf(c1.w * sv);
      *(float4*)&K_sh[r][4 * lane]       = make_float4(kv[0], kv[1], kv[2], kv[3]);
      *(float4*)&K_sh[r][256 + 4 * lane] = make_float4(kv[4], kv[5], kv[6], kv[7]);
      float s = kv[0] + kv[1] + kv[2] + kv[3] + kv[4] + kv[5] + kv[6] + kv[7];
#pragma unroll
      for (int off = 1; off < 64; off <<= 1) s += __shfl_xor(s, off);
      float uu = INVN / s;
      u_last[rr] = uu;
#pragma unroll
      for (int q = 0; q < 8; ++q) colacc[q] = fmaf(kv[q], uu, colacc[q]);
    }
    *(float4*)&scratch_sh[w][4 * lane]       = make_float4(colacc[0], colacc[1], colacc[2], colacc[3]);
    *(float4*)&scratch_sh[w][256 + 4 * lane] = make_float4(colacc[4], colacc[5], colacc[6], colacc[7]);
    __syncthreads();
    float s0 = 0.f;
#pragma unroll
    for (int k = 0; k < 8; ++k) s0 += scratch_sh[k][t];
    store_f32_cg(partrow + t, s0);
  }
  batch_barrier(&cnts[2], &flags[2]);              // iter-1 column partials ready

  // ---- Iterations 2..ITERS ----
  for (int it = 1; it < ITERS; ++it) {
    {  // v-reduce: thread (w2,idx) sums k = 8*w2..8*w2+7 for j-quad idx
      float4 o[8];
      load8x4_s2k_cg(vp1, vp2, o);
      float4 acc = o[0];
      acc.x += o[1].x + o[2].x + o[3].x + o[4].x + o[5].x + o[6].x + o[7].x;
      acc.y += o[1].y + o[2].y + o[3].y + o[4].y + o[5].y + o[6].y + o[7].y;
      acc.z += o[1].z + o[2].z + o[3].z + o[4].z + o[5].z + o[6].z + o[7].z;
      acc.w += o[1].w + o[2].w + o[3].w + o[4].w + o[5].w + o[6].w + o[7].w;
      *(float4*)&scratch_sh[w2][4 * idx] = acc;
    }
    __syncthreads();
    v_sh[t] = INVN / (scratch_sh[0][t] + scratch_sh[1][t] + scratch_sh[2][t] + scratch_sh[3][t]);
    __syncthreads();

    float4 v0 = *(float4*)&v_sh[4 * lane];
    float4 v1 = *(float4*)&v_sh[256 + 4 * lane];
    float vr[8] = {v0.x, v0.y, v0.z, v0.w, v1.x, v1.y, v1.z, v1.w};
    float colacc[8] = {0, 0, 0, 0, 0, 0, 0, 0};
#pragma unroll
    for (int rr = 0; rr < 2; ++rr) {
      int r = 2 * w + rr;
      float4 k0 = *(float4*)&K_sh[r][4 * lane];
      float4 k1 = *(float4*)&K_sh[r][256 + 4 * lane];
      float kv[8] = {k0.x, k0.y, k0.z, k0.w, k1.x, k1.y, k1.z, k1.w};
      float s = 0.f;
#pragma unroll
      for (int q = 0; q < 8; ++q) s = fmaf(kv[q], vr[q], s);
#pragma unroll
      for (int off = 1; off < 64; off <<= 1) s += __shfl_xor(s, off);
      float uu = INVN / s;
      u_last[rr] = uu;
#pragma unroll
      for (int q = 0; q < 8; ++q) colacc[q] = fmaf(kv[q], uu, colacc[q]);
    }
    __syncthreads();
    *(float4*)&scratch_sh[w][4 * lane]       = make_float4(colacc[0], colacc[1], colacc[2], colacc[3]);
    *(float4*)&scratch_sh[w][256 + 4 * lane] = make_float4(colacc[4], colacc[5], colacc[6], colacc[7]);
    __syncthreads();
    float s0 = 0.f;
#pragma unroll
    for (int k = 0; k < 8; ++k) s0 += scratch_sh[k][t];
    store_f32_cg(partrow + t, s0);
    batch_barrier(&cnts[2 + it], &flags[2 + it]);
  }

  // ---- Final: v from last partials; P = u * K * v (plain cached stores) ----
  {
    float4 o[8];
    load8x4_s2k_cg(vp1, vp2, o);
    float4 acc = o[0];
    acc.x += o[1].x + o[2].x + o[3].x + o[4].x + o[5].x + o[6].x + o[7].x;
    acc.y += o[1].y + o[2].y + o[3].y + o[4].y + o[5].y + o[6].y + o[7].y;
    acc.z += o[1].z + o[2].z + o[3].z + o[4].z + o[5].z + o[6].z + o[7].z;
    acc.w += o[1].w + o[2].w + o[3].w + o[4].w + o[5].w + o[6].w + o[7].w;
    *(float4*)&scratch_sh[w2][4 * idx] = acc;
  }
  __syncthreads();
  v_sh[t] = INVN / (scratch_sh[0][t] + scratch_sh[1][t] + scratch_sh[2][t] + scratch_sh[3][t]);
  __syncthreads();
  {
    float4 v0 = *(float4*)&v_sh[4 * lane];
    float4 v1 = *(float4*)&v_sh[256 + 4 * lane];
#pragma unroll
    for (int rr = 0; rr < 2; ++rr) {
      int r = 2 * w + rr;
      float uu = u_last[rr];
      float4 k0 = *(float4*)&K_sh[r][4 * lane];
      float4 k1 = *(float4*)&K_sh[r][256 + 4 * lane];
      float4 o0 = make_float4(uu * k0.x * v0.x, uu * k0.y * v0.y,
                              uu * k0.z * v0.z, uu * k0.w * v0.w);
      float4 o1 = make_float4(uu * k1.x * v1.x, uu * k1.y * v1.y,
                              uu * k1.z * v1.z, uu * k1.w * v1.w);
      float* Prow = P + ((size_t)(b * 512) + r0 + r) * 512;
      *(float4*)(Prow + 4 * lane)       = o0;
      *(float4*)(Prow + 256 + 4 * lane) = o1;
    }
  }
}

extern "C" void kernel_launch(void* const* d_in, const int* in_sizes, int n_in,
                              void* d_out, int out_size, void* d_ws, size_t ws_size,
                              hipStream_t stream) {
  const float* emb_in  = (const float*)d_in[0];
  const void*  maskp   = d_in[1];
  const float* emb_out = (const float*)d_in[2];
  const float* pad     = (const float*)d_in[3];
  const float* pos     = (const float*)d_in[4];
  const float* Win     = (const float*)d_in[5];
  const float* bin     = (const float*)d_in[6];
  const float* Wout    = (const float*)d_in[7];
  const float* bout    = (const float*)d_in[8];
  float* P = (float*)d_out;
  char* ws = (char*)d_ws;

  hipMemsetAsync(ws, 0, 2048, stream);             // zero one-shot barrier slots

  void* args[] = {(void*)&emb_in, (void*)&maskp, (void*)&emb_out, (void*)&pad,
                  (void*)&pos, (void*)&Win, (void*)&bin, (void*)&Wout,
                  (void*)&bout, (void*)&P, (void*)&ws};
  hipLaunchCooperativeKernel((const void*)sinkhorn_one, dim3(256), dim3(512),
                             args, 0, stream);
}

// Round 6
// 70.080 us; speedup vs baseline: 7.8503x; 1.0616x over previous
//
#include <hip/hip_runtime.h>

#define EPS 1e-4f
#define INVN (1.0f/512.0f)

// Two kernels:
//  K1 embed (512 x 256, non-coop, 2 blocks/CU): mask-detect + both GEMVs -> aG, bvG (plain stores)
//  K2 sinkhorn (256 x 512, cooperative): cost->K_sh (LDS-resident) -> S -> exp+u0 -> u1 -> P
//     3 spin-barriers (degree 32, per batch), relaxed agent atomics, zero cache maintenance;
//     cross-block iter data (partsum, parts) via explicit sc0 sc1 (LLC write-through / LLC loads).
//
// ws layout (bytes):
//   [0, 2048)         barrier one-shot slots (memset 0 each launch): batch b at 256*b,
//                     cnt_i @ +4*i, flag_i @ +128+4*i
//   [4096, 5120)      partsum [8][32] f32
//   [8192, 532480)    aG [4096][32] f32  == alias ==  parts_A [8][32][512]
//                     (aG dead before parts_A written: separated by batch barrier 0)
//   [532480, 1056768) bvG [4096][32] f32 == alias ==  parts_B [8][32][512]
//                     (bvG dead before parts_B written: separated by batch barrier 1)
// Generation split A/B fixes rounds 3-5's latent race (in-place parts overwrite was
// ordered only by timing luck, not by a barrier).

__device__ __forceinline__ void store_f32_cg(float* p, float v) {
  asm volatile("global_store_dword %0, %1, off sc0 sc1" :: "v"(p), "v"(v) : "memory");
}

__device__ __forceinline__ float load_f32_cg(const float* p) {
  float r;
  asm volatile("global_load_dword %0, %1, off sc0 sc1\n\t"
               "s_waitcnt vmcnt(0)"
               : "=v"(r) : "v"(p) : "memory");
  return r;
}

// 8 float4 at 2048-byte row stride (k-slices of parts), one wait.
// p1 = base of slice kk=2 (so offsets -4096..+2048 cover kk=0..3), p2 = p1 + 2048 floats (kk=4..7).
__device__ __forceinline__ void load8x4_s2k_cg(const float* p1, const float* p2, float4* o) {
  asm volatile(
      "global_load_dwordx4 %0, %8, off offset:-4096 sc0 sc1\n\t"
      "global_load_dwordx4 %1, %8, off offset:-2048 sc0 sc1\n\t"
      "global_load_dwordx4 %2, %8, off sc0 sc1\n\t"
      "global_load_dwordx4 %3, %8, off offset:2048 sc0 sc1\n\t"
      "global_load_dwordx4 %4, %9, off offset:-4096 sc0 sc1\n\t"
      "global_load_dwordx4 %5, %9, off offset:-2048 sc0 sc1\n\t"
      "global_load_dwordx4 %6, %9, off sc0 sc1\n\t"
      "global_load_dwordx4 %7, %9, off offset:2048 sc0 sc1\n\t"
      "s_waitcnt vmcnt(0)"
      : "=&v"(o[0]), "=&v"(o[1]), "=&v"(o[2]), "=&v"(o[3]),
        "=&v"(o[4]), "=&v"(o[5]), "=&v"(o[6]), "=&v"(o[7])
      : "v"(p1), "v"(p2)
      : "memory");
}

__device__ __forceinline__ void batch_barrier(int* cnt, int* flag) {
  asm volatile("s_waitcnt vmcnt(0)" ::: "memory");   // drain write-through stores to LLC
  __syncthreads();
  if (threadIdx.x == 0) {
    int prev = __hip_atomic_fetch_add(cnt, 1, __ATOMIC_RELAXED, __HIP_MEMORY_SCOPE_AGENT);
    if (prev == 31) {
      __hip_atomic_store(flag, 1, __ATOMIC_RELAXED, __HIP_MEMORY_SCOPE_AGENT);
    } else {
      while (__hip_atomic_load(flag, __ATOMIC_RELAXED, __HIP_MEMORY_SCOPE_AGENT) == 0) {}
    }
  }
  __syncthreads();
}

// ---- Kernel 1: embed GEMVs. 512 blocks x 256 threads, block = 8 nodes x 32 m. ----
__global__ void __launch_bounds__(256)
embed_kernel(const float* __restrict__ emb_in, const void* __restrict__ maskp,
             const float* __restrict__ emb_out, const float* __restrict__ pad,
             const float* __restrict__ pos, const float* __restrict__ Win,
             const float* __restrict__ bin, const float* __restrict__ Wout,
             const float* __restrict__ bout,
             float* __restrict__ aG, float* __restrict__ bvG) {
  const int t = threadIdx.x, blk = blockIdx.x;
  __shared__ unsigned dsh[2];
  __shared__ int mv_sh[8];

  if (t < 2) dsh[t] = 0u;
  __syncthreads();
  {
    // mask element-size detect on first 4096 bytes (dword-wise):
    // bool(1B): bytes i%4!=0 can be nonzero; int32: byte i%8==4 (byte0 of odd words) nonzero; else int64.
    uint4 x = ((const uint4*)maskp)[t];
    unsigned orb = (x.x | x.y | x.z | x.w) & 0xFFFFFF00u;
    unsigned orc = (x.y | x.w) & 0xFFu;
    if (orb) atomicOr(&dsh[0], 1u);
    if (orc) atomicOr(&dsh[1], 1u);
  }
  __syncthreads();
  if (t < 8) {
    int g = blk * 8 + t;
    int mv;
    if (dsh[0])      mv = ((const unsigned char*)maskp)[g];
    else if (dsh[1]) mv = ((const int*)maskp)[g];
    else             mv = (int)(((const long long*)maskp)[g] != 0);
    mv_sh[t] = mv;
  }
  __syncthreads();

  const int r = t >> 5, m = t & 31;
  const int g = blk * 8 + r, n = g & 511;
  const float* eo = emb_out + (size_t)g * 256;
  const float* po = pos + (size_t)n * 256;
  const float* ei = mv_sh[r] ? pad : (emb_in + (size_t)g * 256);
  float aa = bout[m], bb = bin[m];
  for (int d = 0; d < 256; d += 4) {
    float4 e4 = *(const float4*)(eo + d);
    float4 p4 = *(const float4*)(po + d);
    float4 i4 = *(const float4*)(ei + d);
    aa = fmaf(e4.x + p4.x, Wout[(d + 0) * 32 + m], aa);
    aa = fmaf(e4.y + p4.y, Wout[(d + 1) * 32 + m], aa);
    aa = fmaf(e4.z + p4.z, Wout[(d + 2) * 32 + m], aa);
    aa = fmaf(e4.w + p4.w, Wout[(d + 3) * 32 + m], aa);
    bb = fmaf(i4.x, Win[(d + 0) * 32 + m], bb);
    bb = fmaf(i4.y, Win[(d + 1) * 32 + m], bb);
    bb = fmaf(i4.z, Win[(d + 2) * 32 + m], bb);
    bb = fmaf(i4.w, Win[(d + 3) * 32 + m], bb);
  }
  aG[(size_t)g * 32 + m] = aa;
  bvG[(size_t)g * 32 + m] = bb;
}

// ---- Kernel 2: cost + Sinkhorn + P. 256 blocks x 512 threads, cooperative. ----
__global__ void __launch_bounds__(512)
sinkhorn_coop(float* __restrict__ P, char* __restrict__ ws) {
  const int t = threadIdx.x;
  const int blk = blockIdx.x;
  const int b = blk & 7, loc = blk >> 3;     // batch <-> XCD affine (perf heuristic only)
  const int r0 = loc * 16;
  const int w = t >> 6, lane = t & 63;

  int* cnts  = (int*)(ws + 256 * b);
  int* flags = (int*)(ws + 256 * b + 128);
  float* partsumG = (float*)(ws + 4096);
  float* aG      = (float*)(ws + 8192);
  float* partsA  = (float*)(ws + 8192);
  float* bvG     = (float*)(ws + 532480);
  float* partsB  = (float*)(ws + 532480);

  __shared__ float K_sh[16][512];        // 32 KB: C -> K, block-resident through P
  __shared__ float scratch_sh[8][512];   // 16 KB: colacc rows / v-reduce rows
  __shared__ float v_sh[512];
  __shared__ float a_sh[16][32];
  __shared__ float red_sh[8];
  __shared__ float sv_sh;

  // ---- Phase a: stage own a-rows (2 KB) + own bv column (plain cached loads) ----
  float bva[32];
  {
    const float4* bj = (const float4*)(bvG + ((size_t)(b * 512) + t) * 32);
    float4 bq0 = bj[0], bq1 = bj[1], bq2 = bj[2], bq3 = bj[3];
    float4 bq4 = bj[4], bq5 = bj[5], bq6 = bj[6], bq7 = bj[7];
    ((float*)a_sh)[t] = aG[(size_t)(b * 512 + r0) * 32 + t];
    bva[0]=bq0.x; bva[1]=bq0.y; bva[2]=bq0.z; bva[3]=bq0.w;
    bva[4]=bq1.x; bva[5]=bq1.y; bva[6]=bq1.z; bva[7]=bq1.w;
    bva[8]=bq2.x; bva[9]=bq2.y; bva[10]=bq2.z; bva[11]=bq2.w;
    bva[12]=bq3.x; bva[13]=bq3.y; bva[14]=bq3.z; bva[15]=bq3.w;
    bva[16]=bq4.x; bva[17]=bq4.y; bva[18]=bq4.z; bva[19]=bq4.w;
    bva[20]=bq5.x; bva[21]=bq5.y; bva[22]=bq5.z; bva[23]=bq5.w;
    bva[24]=bq6.x; bva[25]=bq6.y; bva[26]=bq6.z; bva[27]=bq6.w;
    bva[28]=bq7.x; bva[29]=bq7.y; bva[30]=bq7.z; bva[31]=bq7.w;
  }
  __syncthreads();

  // ---- Phase b: C tile (16 rows x 512 cols), one column per thread, + partial sum ----
  {
    float csum = 0.f;
    for (int r = 0; r < 16; ++r) {
      const float4* ar4 = (const float4*)&a_sh[r][0];   // LDS broadcast reads
      float c0 = 0.f;
#pragma unroll
      for (int q = 0; q < 8; ++q) {
        float4 av = ar4[q];
        c0 += fabsf(av.x - bva[q * 4 + 0]) + fabsf(av.y - bva[q * 4 + 1])
            + fabsf(av.z - bva[q * 4 + 2]) + fabsf(av.w - bva[q * 4 + 3]);
      }
      K_sh[r][t] = c0;
      csum += c0;
    }
#pragma unroll
    for (int off = 1; off < 64; off <<= 1) csum += __shfl_xor(csum, off);
    if (lane == 0) red_sh[w] = csum;
    __syncthreads();
    if (t == 0) {
      float s = 0.f;
#pragma unroll
      for (int k = 0; k < 8; ++k) s += red_sh[k];
      store_f32_cg(partsumG + b * 32 + loc, s);
    }
  }
  batch_barrier(&cnts[0], &flags[0]);              // bar0: cost partials ready (aG dead)

  // ---- sv = -1/(EPS*S) ----
  if (t < 64) {
    float pv = (t < 32) ? load_f32_cg(partsumG + b * 32 + t) : 0.f;
#pragma unroll
    for (int off = 1; off < 64; off <<= 1) pv += __shfl_xor(pv, off);
    if (t == 0) sv_sh = -1.0f / (EPS * pv);
  }
  __syncthreads();
  const float sv = sv_sh;

  float u_last[2];
  const int w2 = t >> 7, idx = t & 127;
  float* partrowA = partsA + ((size_t)(b * 32) + loc) * 512;
  float* partrowB = partsB + ((size_t)(b * 32) + loc) * 512;
  const float* vpA1 = partsA + (size_t)b * 32 * 512 + (size_t)(w2 * 8) * 512 + idx * 4 + 1024;
  const float* vpA2 = vpA1 + 2048;
  const float* vpB1 = partsB + (size_t)b * 32 * 512 + (size_t)(w2 * 8) * 512 + idx * 4 + 1024;
  const float* vpB2 = vpB1 + 2048;

  // ---- Phase c: K = exp(C*sv), u0 (v==1), column partials -> parts_A ----
  {
    float colacc[8] = {0, 0, 0, 0, 0, 0, 0, 0};
#pragma unroll
    for (int rr = 0; rr < 2; ++rr) {
      int r = 2 * w + rr;
      float4 c0 = *(float4*)&K_sh[r][4 * lane];
      float4 c1 = *(float4*)&K_sh[r][256 + 4 * lane];
      float kv[8];
      kv[0] = __expf(c0.x * sv); kv[1] = __expf(c0.y * sv);
      kv[2] = __expf(c0.z * sv); kv[3] = __expf(c0.w * sv);
      kv[4] = __expf(c1.x * sv); kv[5] = __expf(c1.y * sv);
      kv[6] = __expf(c1.z * sv); kv[7] = __expf(c1.w * sv);
      *(float4*)&K_sh[r][4 * lane]       = make_float4(kv[0], kv[1], kv[2], kv[3]);
      *(float4*)&K_sh[r][256 + 4 * lane] = make_float4(kv[4], kv[5], kv[6], kv[7]);
      float s = kv[0] + kv[1] + kv[2] + kv[3] + kv[4] + kv[5] + kv[6] + kv[7];
#pragma unroll
      for (int off = 1; off < 64; off <<= 1) s += __shfl_xor(s, off);
      float uu = INVN / s;
      u_last[rr] = uu;
#pragma unroll
      for (int q = 0; q < 8; ++q) colacc[q] = fmaf(kv[q], uu, colacc[q]);
    }
    *(float4*)&scratch_sh[w][4 * lane]       = make_float4(colacc[0], colacc[1], colacc[2], colacc[3]);
    *(float4*)&scratch_sh[w][256 + 4 * lane] = make_float4(colacc[4], colacc[5], colacc[6], colacc[7]);
    __syncthreads();
    float s0 = 0.f;
#pragma unroll
    for (int k = 0; k < 8; ++k) s0 += scratch_sh[k][t];
    store_f32_cg(partrowA + t, s0);
  }
  batch_barrier(&cnts[1], &flags[1]);              // bar1: parts_A ready (bvG dead)

  // ---- Phase d: v1 from parts_A; u1; column partials -> parts_B ----
  {
    float4 o[8];
    load8x4_s2k_cg(vpA1, vpA2, o);
    float4 acc = o[0];
    acc.x += o[1].x + o[2].x + o[3].x + o[4].x + o[5].x + o[6].x + o[7].x;
    acc.y += o[1].y + o[2].y + o[3].y + o[4].y + o[5].y + o[6].y + o[7].y;
    acc.z += o[1].z + o[2].z + o[3].z + o[4].z + o[5].z + o[6].z + o[7].z;
    acc.w += o[1].w + o[2].w + o[3].w + o[4].w + o[5].w + o[6].w + o[7].w;
    *(float4*)&scratch_sh[w2][4 * idx] = acc;
  }
  __syncthreads();
  v_sh[t] = INVN / (scratch_sh[0][t] + scratch_sh[1][t] + scratch_sh[2][t] + scratch_sh[3][t]);
  __syncthreads();
  {
    float4 v0 = *(float4*)&v_sh[4 * lane];
    float4 v1 = *(float4*)&v_sh[256 + 4 * lane];
    float vr[8] = {v0.x, v0.y, v0.z, v0.w, v1.x, v1.y, v1.z, v1.w};
    float colacc[8] = {0, 0, 0, 0, 0, 0, 0, 0};
#pragma unroll
    for (int rr = 0; rr < 2; ++rr) {
      int r = 2 * w + rr;
      float4 k0 = *(float4*)&K_sh[r][4 * lane];
      float4 k1 = *(float4*)&K_sh[r][256 + 4 * lane];
      float kv[8] = {k0.x, k0.y, k0.z, k0.w, k1.x, k1.y, k1.z, k1.w};
      float s = 0.f;
#pragma unroll
      for (int q = 0; q < 8; ++q) s = fmaf(kv[q], vr[q], s);
#pragma unroll
      for (int off = 1; off < 64; off <<= 1) s += __shfl_xor(s, off);
      float uu = INVN / s;
      u_last[rr] = uu;
#pragma unroll
      for (int q = 0; q < 8; ++q) colacc[q] = fmaf(kv[q], uu, colacc[q]);
    }
    __syncthreads();
    *(float4*)&scratch_sh[w][4 * lane]       = make_float4(colacc[0], colacc[1], colacc[2], colacc[3]);
    *(float4*)&scratch_sh[w][256 + 4 * lane] = make_float4(colacc[4], colacc[5], colacc[6], colacc[7]);
    __syncthreads();
    float s0 = 0.f;
#pragma unroll
    for (int k = 0; k < 8; ++k) s0 += scratch_sh[k][t];
    store_f32_cg(partrowB + t, s0);
  }
  batch_barrier(&cnts[2], &flags[2]);              // bar2: parts_B ready

  // ---- Phase e: v2 from parts_B; P = u1 * K * v2 ----
  {
    float4 o[8];
    load8x4_s2k_cg(vpB1, vpB2, o);
    float4 acc = o[0];
    acc.x += o[1].x + o[2].x + o[3].x + o[4].x + o[5].x + o[6].x + o[7].x;
    acc.y += o[1].y + o[2].y + o[3].y + o[4].y + o[5].y + o[6].y + o[7].y;
    acc.z += o[1].z + o[2].z + o[3].z + o[4].z + o[5].z + o[6].z + o[7].z;
    acc.w += o[1].w + o[2].w + o[3].w + o[4].w + o[5].w + o[6].w + o[7].w;
    *(float4*)&scratch_sh[w2][4 * idx] = acc;
  }
  __syncthreads();
  v_sh[t] = INVN / (scratch_sh[0][t] + scratch_sh[1][t] + scratch_sh[2][t] + scratch_sh[3][t]);
  __syncthreads();
  {
    float4 v0 = *(float4*)&v_sh[4 * lane];
    float4 v1 = *(float4*)&v_sh[256 + 4 * lane];
#pragma unroll
    for (int rr = 0; rr < 2; ++rr) {
      int r = 2 * w + rr;
      float uu = u_last[rr];
      float4 k0 = *(float4*)&K_sh[r][4 * lane];
      float4 k1 = *(float4*)&K_sh[r][256 + 4 * lane];
      float4 o0 = make_float4(uu * k0.x * v0.x, uu * k0.y * v0.y,
                              uu * k0.z * v0.z, uu * k0.w * v0.w);
      float4 o1 = make_float4(uu * k1.x * v1.x, uu * k1.y * v1.y,
                              uu * k1.z * v1.z, uu * k1.w * v1.w);
      float* Prow = P + ((size_t)(b * 512) + r0 + r) * 512;
      *(float4*)(Prow + 4 * lane)       = o0;
      *(float4*)(Prow + 256 + 4 * lane) = o1;
    }
  }
}

extern "C" void kernel_launch(void* const* d_in, const int* in_sizes, int n_in,
                              void* d_out, int out_size, void* d_ws, size_t ws_size,
                              hipStream_t stream) {
  const float* emb_in  = (const float*)d_in[0];
  const void*  maskp   = d_in[1];
  const float* emb_out = (const float*)d_in[2];
  const float* pad     = (const float*)d_in[3];
  const float* pos     = (const float*)d_in[4];
  const float* Win     = (const float*)d_in[5];
  const float* bin     = (const float*)d_in[6];
  const float* Wout    = (const float*)d_in[7];
  const float* bout    = (const float*)d_in[8];
  float* P = (float*)d_out;
  char* ws = (char*)d_ws;
  float* aG  = (float*)(ws + 8192);
  float* bvG = (float*)(ws + 532480);

  hipMemsetAsync(ws, 0, 2048, stream);             // zero one-shot barrier slots

  embed_kernel<<<512, 256, 0, stream>>>(emb_in, maskp, emb_out, pad, pos,
                                        Win, bin, Wout, bout, aG, bvG);

  void* args[] = {(void*)&P, (void*)&ws};
  hipLaunchCooperativeKernel((const void*)sinkhorn_coop, dim3(256), dim3(512),
                             args, 0, stream);
}

// Round 7
// 43.252 us; speedup vs baseline: 12.7197x; 1.6203x over previous
//
#include <hip/hip_runtime.h>

#define EPS 1e-4f
#define INVN (1.0f/512.0f)

// Two kernels, both REGULAR launches (graph = 2 nodes, no memset, no coop ramp):
//  K1 embed (512 x 256, 2+ blocks/CU): mask-detect + both GEMVs -> aG, bvG (plain stores);
//     block 0 also zeroes the barrier slots (sc0 sc1 write-through -> LLC) for K2.
//  K2 sinkhorn (256 x 512, 1 block/CU co-resident by capacity: VGPR 40, LDS 54KB -> >=2 blocks/CU
//     possible, so all 256 blocks resident immediately): cost->K_sh (LDS) -> S -> exp+u0 -> u1 -> P.
//     3 spin-barriers (degree 32, per batch), relaxed agent atomics, zero cache maintenance;
//     cross-block data (partsum, parts) via explicit sc0 sc1 (LLC write-through / LLC loads).
//
// ws layout (bytes):
//   [0, 2048)         barrier one-shot slots (zeroed by K1 each launch): batch b at 256*b,
//                     cnt_i @ +4*i, flag_i @ +128+4*i
//   [4096, 5120)      partsum [8][32] f32
//   [8192, 532480)    aG [4096][32] f32  == alias ==  parts_A [8][32][512]
//                     (aG dead before parts_A written: separated by batch barrier 0)
//   [532480, 1056768) bvG [4096][32] f32 == alias ==  parts_B [8][32][512]
//                     (bvG dead before parts_B written: separated by batch barrier 1)

__device__ __forceinline__ void store_f32_cg(float* p, float v) {
  asm volatile("global_store_dword %0, %1, off sc0 sc1" :: "v"(p), "v"(v) : "memory");
}

__device__ __forceinline__ float load_f32_cg(const float* p) {
  float r;
  asm volatile("global_load_dword %0, %1, off sc0 sc1\n\t"
               "s_waitcnt vmcnt(0)"
               : "=v"(r) : "v"(p) : "memory");
  return r;
}

// 8 float4 at 2048-byte row stride (k-slices of parts), one wait.
// p1 = base of slice kk=2 (offsets -4096..+2048 cover kk=0..3), p2 = p1 + 2048 floats (kk=4..7).
__device__ __forceinline__ void load8x4_s2k_cg(const float* p1, const float* p2, float4* o) {
  asm volatile(
      "global_load_dwordx4 %0, %8, off offset:-4096 sc0 sc1\n\t"
      "global_load_dwordx4 %1, %8, off offset:-2048 sc0 sc1\n\t"
      "global_load_dwordx4 %2, %8, off sc0 sc1\n\t"
      "global_load_dwordx4 %3, %8, off offset:2048 sc0 sc1\n\t"
      "global_load_dwordx4 %4, %9, off offset:-4096 sc0 sc1\n\t"
      "global_load_dwordx4 %5, %9, off offset:-2048 sc0 sc1\n\t"
      "global_load_dwordx4 %6, %9, off sc0 sc1\n\t"
      "global_load_dwordx4 %7, %9, off offset:2048 sc0 sc1\n\t"
      "s_waitcnt vmcnt(0)"
      : "=&v"(o[0]), "=&v"(o[1]), "=&v"(o[2]), "=&v"(o[3]),
        "=&v"(o[4]), "=&v"(o[5]), "=&v"(o[6]), "=&v"(o[7])
      : "v"(p1), "v"(p2)
      : "memory");
}

__device__ __forceinline__ void batch_barrier(int* cnt, int* flag) {
  asm volatile("s_waitcnt vmcnt(0)" ::: "memory");   // drain write-through stores to LLC
  __syncthreads();
  if (threadIdx.x == 0) {
    int prev = __hip_atomic_fetch_add(cnt, 1, __ATOMIC_RELAXED, __HIP_MEMORY_SCOPE_AGENT);
    if (prev == 31) {
      __hip_atomic_store(flag, 1, __ATOMIC_RELAXED, __HIP_MEMORY_SCOPE_AGENT);
    } else {
      while (__hip_atomic_load(flag, __ATOMIC_RELAXED, __HIP_MEMORY_SCOPE_AGENT) == 0) {}
    }
  }
  __syncthreads();
}

// ---- Kernel 1: embed GEMVs. 512 blocks x 256 threads, block = 8 nodes x 32 m. ----
__global__ void __launch_bounds__(256)
embed_kernel(const float* __restrict__ emb_in, const void* __restrict__ maskp,
             const float* __restrict__ emb_out, const float* __restrict__ pad,
             const float* __restrict__ pos, const float* __restrict__ Win,
             const float* __restrict__ bin, const float* __restrict__ Wout,
             const float* __restrict__ bout,
             float* __restrict__ aG, float* __restrict__ bvG,
             char* __restrict__ ws) {
  const int t = threadIdx.x, blk = blockIdx.x;
  __shared__ unsigned dsh[2];
  __shared__ int mv_sh[8];

  if (blk == 0 && t < 256) {           // zero barrier slots for K2 (write-through to LLC)
    store_f32_cg((float*)(ws + 4 * t), 0.0f);
    store_f32_cg((float*)(ws + 1024 + 4 * t), 0.0f);
  }

  if (t < 2) dsh[t] = 0u;
  __syncthreads();
  {
    // mask element-size detect on first 4096 bytes (dword-wise):
    // bool(1B): any byte i%4!=0 nonzero; int32: low byte of odd dwords nonzero; else int64.
    uint4 x = ((const uint4*)maskp)[t];
    unsigned orb = (x.x | x.y | x.z | x.w) & 0xFFFFFF00u;
    unsigned orc = (x.y | x.w) & 0xFFu;
    if (orb) atomicOr(&dsh[0], 1u);
    if (orc) atomicOr(&dsh[1], 1u);
  }
  __syncthreads();
  if (t < 8) {
    int g = blk * 8 + t;
    int mv;
    if (dsh[0])      mv = ((const unsigned char*)maskp)[g];
    else if (dsh[1]) mv = ((const int*)maskp)[g];
    else             mv = (int)(((const long long*)maskp)[g] != 0);
    mv_sh[t] = mv;
  }
  __syncthreads();

  const int r = t >> 5, m = t & 31;
  const int g = blk * 8 + r, n = g & 511;
  const float* eo = emb_out + (size_t)g * 256;
  const float* po = pos + (size_t)n * 256;
  const float* ei = mv_sh[r] ? pad : (emb_in + (size_t)g * 256);
  float aa = bout[m], bb = bin[m];
  for (int d = 0; d < 256; d += 4) {
    float4 e4 = *(const float4*)(eo + d);
    float4 p4 = *(const float4*)(po + d);
    float4 i4 = *(const float4*)(ei + d);
    aa = fmaf(e4.x + p4.x, Wout[(d + 0) * 32 + m], aa);
    aa = fmaf(e4.y + p4.y, Wout[(d + 1) * 32 + m], aa);
    aa = fmaf(e4.z + p4.z, Wout[(d + 2) * 32 + m], aa);
    aa = fmaf(e4.w + p4.w, Wout[(d + 3) * 32 + m], aa);
    bb = fmaf(i4.x, Win[(d + 0) * 32 + m], bb);
    bb = fmaf(i4.y, Win[(d + 1) * 32 + m], bb);
    bb = fmaf(i4.z, Win[(d + 2) * 32 + m], bb);
    bb = fmaf(i4.w, Win[(d + 3) * 32 + m], bb);
  }
  aG[(size_t)g * 32 + m] = aa;
  bvG[(size_t)g * 32 + m] = bb;
}

// ---- Kernel 2: cost + Sinkhorn + P. 256 blocks x 512 threads, REGULAR launch. ----
__global__ void __launch_bounds__(512)
sinkhorn_main(float* __restrict__ P, char* __restrict__ ws) {
  const int t = threadIdx.x;
  const int blk = blockIdx.x;
  const int b = blk & 7, loc = blk >> 3;     // batch <-> XCD affine (perf heuristic only)
  const int r0 = loc * 16;
  const int w = t >> 6, lane = t & 63;

  int* cnts  = (int*)(ws + 256 * b);
  int* flags = (int*)(ws + 256 * b + 128);
  float* partsumG = (float*)(ws + 4096);
  float* aG      = (float*)(ws + 8192);
  float* partsA  = (float*)(ws + 8192);
  float* bvG     = (float*)(ws + 532480);
  float* partsB  = (float*)(ws + 532480);

  __shared__ float K_sh[16][512];        // 32 KB: C -> K, block-resident through P
  __shared__ float scratch_sh[8][512];   // 16 KB: colacc rows / v-reduce rows
  __shared__ float v_sh[512];
  __shared__ float a_sh[16][32];
  __shared__ float red_sh[8];
  __shared__ float sv_sh;

  // ---- Phase a: stage own a-rows (2 KB) + own bv column (plain cached loads) ----
  float bva[32];
  {
    const float4* bj = (const float4*)(bvG + ((size_t)(b * 512) + t) * 32);
    float4 bq0 = bj[0], bq1 = bj[1], bq2 = bj[2], bq3 = bj[3];
    float4 bq4 = bj[4], bq5 = bj[5], bq6 = bj[6], bq7 = bj[7];
    ((float*)a_sh)[t] = aG[(size_t)(b * 512 + r0) * 32 + t];
    bva[0]=bq0.x; bva[1]=bq0.y; bva[2]=bq0.z; bva[3]=bq0.w;
    bva[4]=bq1.x; bva[5]=bq1.y; bva[6]=bq1.z; bva[7]=bq1.w;
    bva[8]=bq2.x; bva[9]=bq2.y; bva[10]=bq2.z; bva[11]=bq2.w;
    bva[12]=bq3.x; bva[13]=bq3.y; bva[14]=bq3.z; bva[15]=bq3.w;
    bva[16]=bq4.x; bva[17]=bq4.y; bva[18]=bq4.z; bva[19]=bq4.w;
    bva[20]=bq5.x; bva[21]=bq5.y; bva[22]=bq5.z; bva[23]=bq5.w;
    bva[24]=bq6.x; bva[25]=bq6.y; bva[26]=bq6.z; bva[27]=bq6.w;
    bva[28]=bq7.x; bva[29]=bq7.y; bva[30]=bq7.z; bva[31]=bq7.w;
  }
  __syncthreads();

  // ---- Phase b: C tile (16 rows x 512 cols), one column per thread, + partial sum ----
  {
    float csum = 0.f;
    for (int r = 0; r < 16; ++r) {
      const float4* ar4 = (const float4*)&a_sh[r][0];   // LDS broadcast reads
      float c0 = 0.f;
#pragma unroll
      for (int q = 0; q < 8; ++q) {
        float4 av = ar4[q];
        c0 += fabsf(av.x - bva[q * 4 + 0]) + fabsf(av.y - bva[q * 4 + 1])
            + fabsf(av.z - bva[q * 4 + 2]) + fabsf(av.w - bva[q * 4 + 3]);
      }
      K_sh[r][t] = c0;
      csum += c0;
    }
#pragma unroll
    for (int off = 1; off < 64; off <<= 1) csum += __shfl_xor(csum, off);
    if (lane == 0) red_sh[w] = csum;
    __syncthreads();
    if (t == 0) {
      float s = 0.f;
#pragma unroll
      for (int k = 0; k < 8; ++k) s += red_sh[k];
      store_f32_cg(partsumG + b * 32 + loc, s);
    }
  }
  batch_barrier(&cnts[0], &flags[0]);              // bar0: cost partials ready (aG dead)

  // ---- sv = -1/(EPS*S) ----
  if (t < 64) {
    float pv = (t < 32) ? load_f32_cg(partsumG + b * 32 + t) : 0.f;
#pragma unroll
    for (int off = 1; off < 64; off <<= 1) pv += __shfl_xor(pv, off);
    if (t == 0) sv_sh = -1.0f / (EPS * pv);
  }
  __syncthreads();
  const float sv = sv_sh;

  float u_last[2];
  const int w2 = t >> 7, idx = t & 127;
  float* partrowA = partsA + ((size_t)(b * 32) + loc) * 512;
  float* partrowB = partsB + ((size_t)(b * 32) + loc) * 512;
  const float* vpA1 = partsA + (size_t)b * 32 * 512 + (size_t)(w2 * 8) * 512 + idx * 4 + 1024;
  const float* vpA2 = vpA1 + 2048;
  const float* vpB1 = partsB + (size_t)b * 32 * 512 + (size_t)(w2 * 8) * 512 + idx * 4 + 1024;
  const float* vpB2 = vpB1 + 2048;

  // ---- Phase c: K = exp(C*sv), u0 (v==1), column partials -> parts_A ----
  {
    float colacc[8] = {0, 0, 0, 0, 0, 0, 0, 0};
#pragma unroll
    for (int rr = 0; rr < 2; ++rr) {
      int r = 2 * w + rr;
      float4 c0 = *(float4*)&K_sh[r][4 * lane];
      float4 c1 = *(float4*)&K_sh[r][256 + 4 * lane];
      float kv[8];
      kv[0] = __expf(c0.x * sv); kv[1] = __expf(c0.y * sv);
      kv[2] = __expf(c0.z * sv); kv[3] = __expf(c0.w * sv);
      kv[4] = __expf(c1.x * sv); kv[5] = __expf(c1.y * sv);
      kv[6] = __expf(c1.z * sv); kv[7] = __expf(c1.w * sv);
      *(float4*)&K_sh[r][4 * lane]       = make_float4(kv[0], kv[1], kv[2], kv[3]);
      *(float4*)&K_sh[r][256 + 4 * lane] = make_float4(kv[4], kv[5], kv[6], kv[7]);
      float s = kv[0] + kv[1] + kv[2] + kv[3] + kv[4] + kv[5] + kv[6] + kv[7];
#pragma unroll
      for (int off = 1; off < 64; off <<= 1) s += __shfl_xor(s, off);
      float uu = INVN / s;
      u_last[rr] = uu;
#pragma unroll
      for (int q = 0; q < 8; ++q) colacc[q] = fmaf(kv[q], uu, colacc[q]);
    }
    *(float4*)&scratch_sh[w][4 * lane]       = make_float4(colacc[0], colacc[1], colacc[2], colacc[3]);
    *(float4*)&scratch_sh[w][256 + 4 * lane] = make_float4(colacc[4], colacc[5], colacc[6], colacc[7]);
    __syncthreads();
    float s0 = 0.f;
#pragma unroll
    for (int k = 0; k < 8; ++k) s0 += scratch_sh[k][t];
    store_f32_cg(partrowA + t, s0);
  }
  batch_barrier(&cnts[1], &flags[1]);              // bar1: parts_A ready (bvG dead)

  // ---- Phase d: v1 from parts_A; u1; column partials -> parts_B ----
  {
    float4 o[8];
    load8x4_s2k_cg(vpA1, vpA2, o);
    float4 acc = o[0];
    acc.x += o[1].x + o[2].x + o[3].x + o[4].x + o[5].x + o[6].x + o[7].x;
    acc.y += o[1].y + o[2].y + o[3].y + o[4].y + o[5].y + o[6].y + o[7].y;
    acc.z += o[1].z + o[2].z + o[3].z + o[4].z + o[5].z + o[6].z + o[7].z;
    acc.w += o[1].w + o[2].w + o[3].w + o[4].w + o[5].w + o[6].w + o[7].w;
    *(float4*)&scratch_sh[w2][4 * idx] = acc;
  }
  __syncthreads();
  v_sh[t] = INVN / (scratch_sh[0][t] + scratch_sh[1][t] + scratch_sh[2][t] + scratch_sh[3][t]);
  __syncthreads();
  {
    float4 v0 = *(float4*)&v_sh[4 * lane];
    float4 v1 = *(float4*)&v_sh[256 + 4 * lane];
    float vr[8] = {v0.x, v0.y, v0.z, v0.w, v1.x, v1.y, v1.z, v1.w};
    float colacc[8] = {0, 0, 0, 0, 0, 0, 0, 0};
#pragma unroll
    for (int rr = 0; rr < 2; ++rr) {
      int r = 2 * w + rr;
      float4 k0 = *(float4*)&K_sh[r][4 * lane];
      float4 k1 = *(float4*)&K_sh[r][256 + 4 * lane];
      float kv[8] = {k0.x, k0.y, k0.z, k0.w, k1.x, k1.y, k1.z, k1.w};
      float s = 0.f;
#pragma unroll
      for (int q = 0; q < 8; ++q) s = fmaf(kv[q], vr[q], s);
#pragma unroll
      for (int off = 1; off < 64; off <<= 1) s += __shfl_xor(s, off);
      float uu = INVN / s;
      u_last[rr] = uu;
#pragma unroll
      for (int q = 0; q < 8; ++q) colacc[q] = fmaf(kv[q], uu, colacc[q]);
    }
    __syncthreads();
    *(float4*)&scratch_sh[w][4 * lane]       = make_float4(colacc[0], colacc[1], colacc[2], colacc[3]);
    *(float4*)&scratch_sh[w][256 + 4 * lane] = make_float4(colacc[4], colacc[5], colacc[6], colacc[7]);
    __syncthreads();
    float s0 = 0.f;
#pragma unroll
    for (int k = 0; k < 8; ++k) s0 += scratch_sh[k][t];
    store_f32_cg(partrowB + t, s0);
  }
  batch_barrier(&cnts[2], &flags[2]);              // bar2: parts_B ready

  // ---- Phase e: v2 from parts_B; P = u1 * K * v2 ----
  {
    float4 o[8];
    load8x4_s2k_cg(vpB1, vpB2, o);
    float4 acc = o[0];
    acc.x += o[1].x + o[2].x + o[3].x + o[4].x + o[5].x + o[6].x + o[7].x;
    acc.y += o[1].y + o[2].y + o[3].y + o[4].y + o[5].y + o[6].y + o[7].y;
    acc.z += o[1].z + o[2].z + o[3].z + o[4].z + o[5].z + o[6].z + o[7].z;
    acc.w += o[1].w + o[2].w + o[3].w + o[4].w + o[5].w + o[6].w + o[7].w;
    *(float4*)&scratch_sh[w2][4 * idx] = acc;
  }
  __syncthreads();
  v_sh[t] = INVN / (scratch_sh[0][t] + scratch_sh[1][t] + scratch_sh[2][t] + scratch_sh[3][t]);
  __syncthreads();
  {
    float4 v0 = *(float4*)&v_sh[4 * lane];
    float4 v1 = *(float4*)&v_sh[256 + 4 * lane];
#pragma unroll
    for (int rr = 0; rr < 2; ++rr) {
      int r = 2 * w + rr;
      float uu = u_last[rr];
      float4 k0 = *(float4*)&K_sh[r][4 * lane];
      float4 k1 = *(float4*)&K_sh[r][256 + 4 * lane];
      float4 o0 = make_float4(uu * k0.x * v0.x, uu * k0.y * v0.y,
                              uu * k0.z * v0.z, uu * k0.w * v0.w);
      float4 o1 = make_float4(uu * k1.x * v1.x, uu * k1.y * v1.y,
                              uu * k1.z * v1.z, uu * k1.w * v1.w);
      float* Prow = P + ((size_t)(b * 512) + r0 + r) * 512;
      *(float4*)(Prow + 4 * lane)       = o0;
      *(float4*)(Prow + 256 + 4 * lane) = o1;
    }
  }
}

extern "C" void kernel_launch(void* const* d_in, const int* in_sizes, int n_in,
                              void* d_out, int out_size, void* d_ws, size_t ws_size,
                              hipStream_t stream) {
  const float* emb_in  = (const float*)d_in[0];
  const void*  maskp   = d_in[1];
  const float* emb_out = (const float*)d_in[2];
  const float* pos     = (const float*)d_in[4];
  const float* pad     = (const float*)d_in[3];
  const float* Win     = (const float*)d_in[5];
  const float* bin     = (const float*)d_in[6];
  const float* Wout    = (const float*)d_in[7];
  const float* bout    = (const float*)d_in[8];
  float* P = (float*)d_out;
  char* ws = (char*)d_ws;
  float* aG  = (float*)(ws + 8192);
  float* bvG = (float*)(ws + 532480);

  embed_kernel<<<512, 256, 0, stream>>>(emb_in, maskp, emb_out, pad, pos,
                                        Win, bin, Wout, bout, aG, bvG, ws);
  sinkhorn_main<<<256, 512, 0, stream>>>(P, ws);
}